// Round 6
// baseline (2879.800 us; speedup 1.0000x reference)
//
#include <hip/hip_runtime.h>
#include <math.h>

#define N_NODES 15000
#define NPAD    15104      // 118*128
#define E_EDGES 240000
#define IN_DIM  100
#define HID     128
#define N_ETYPES 13
#define N_STEPS  6
#define N_GRAPHS 64
#define N_CLASSES 10
#define NBUCK   (118 * N_ETYPES)   // 1534 (dst-block, etype) buckets

typedef short v8bf __attribute__((ext_vector_type(8)));
typedef float v4f  __attribute__((ext_vector_type(4)));

union FragU { uint4 u; v8bf b; };

static __device__ __forceinline__ float bf2f(unsigned short u) {
    union { unsigned int i; float f; } x; x.i = ((unsigned int)u) << 16; return x.f;
}
static __device__ __forceinline__ unsigned short f2bf(float f) {
    union { float f; unsigned int i; } x; x.f = f;
    unsigned int u = x.i;
    u = (u + 0x7fff + ((u >> 16) & 1)) >> 16;   // round-nearest-even
    return (unsigned short)u;
}
static __device__ __forceinline__ float sigm(float x) { return 1.f / (1.f + expf(-x)); }

// ---------------- misc ----------------
__global__ __launch_bounds__(256) void k_zero(float* __restrict__ p, long n4) {
    long i = (long)blockIdx.x * 256 + threadIdx.x;
    if (i < n4) ((float4*)p)[i] = make_float4(0.f, 0.f, 0.f, 0.f);
}

__global__ __launch_bounds__(256) void k_init_h(const float* __restrict__ feat,
                                                float* __restrict__ h32,
                                                unsigned short* __restrict__ h_hi,
                                                unsigned short* __restrict__ h_lo) {
    int idx = blockIdx.x * 256 + threadIdx.x;
    if (idx >= NPAD * HID) return;
    int n = idx >> 7, c = idx & 127;
    float v = 0.f;
    if (n < N_NODES && c < IN_DIM) v = feat[n * IN_DIM + c];
    h32[idx] = v;
    unsigned short hi = f2bf(v);
    h_hi[idx] = hi;
    h_lo[idx] = f2bf(v - bf2f(hi));
}

// Weights -> bf16 hi/lo MFMA-fragment planes.
// Frag layout for B[128 x NC]: frag id = kcsub*NC + col (kcsub 0..15), 8 bf16 k=kcsub*8+j.
__global__ __launch_bounds__(256) void k_prepW(
    const float* __restrict__ W_e, const float* __restrict__ W_ih, const float* __restrict__ W_hh,
    unsigned short* __restrict__ WeH, unsigned short* __restrict__ WeL,
    unsigned short* __restrict__ WihH, unsigned short* __restrict__ WihL,
    unsigned short* __restrict__ WhhH, unsigned short* __restrict__ WhhL)
{
    int f = blockIdx.x * 256 + threadIdx.x;
    const int NE = N_ETYPES * 2048;
    const int NG = 16 * 384;
    unsigned short th[8], tl[8];
    if (f < NE) {
        int t = f >> 11, r = f & 2047, kcsub = r >> 7, c = r & 127;
        #pragma unroll
        for (int j = 0; j < 8; ++j) {
            float w = W_e[(long)t * 16384 + (kcsub * 8 + j) * 128 + c];
            th[j] = f2bf(w); tl[j] = f2bf(w - bf2f(th[j]));
        }
        long off = (long)t * 16384 + ((kcsub << 7) + c) * 8;
        *(uint4*)(WeH + off) = *(uint4*)th;
        *(uint4*)(WeL + off) = *(uint4*)tl;
    } else if (f < NE + 2 * NG) {
        int f2 = f - NE;
        const float* srcp = (f2 < NG) ? W_ih : W_hh;
        unsigned short* dh = (f2 < NG) ? WihH : WhhH;
        unsigned short* dl = (f2 < NG) ? WihL : WhhL;
        int g = (f2 < NG) ? f2 : f2 - NG;
        int kcsub = g / 384, c = g - kcsub * 384;
        #pragma unroll
        for (int j = 0; j < 8; ++j) {
            float w = srcp[(long)c * 128 + kcsub * 8 + j];   // B[k][c] = W[c][k]
            th[j] = f2bf(w); tl[j] = f2bf(w - bf2f(th[j]));
        }
        long off = ((long)kcsub * 384 + c) * 8;
        *(uint4*)(dh + off) = *(uint4*)th;
        *(uint4*)(dl + off) = *(uint4*)tl;
    }
}

// ---------------- edge bucketing by (dst>>7, etype) ----------------
__global__ __launch_bounds__(256) void k_count2(const int* __restrict__ dst, const int* __restrict__ et,
                                                int* __restrict__ bdeg, int* __restrict__ cntT) {
    int e = blockIdx.x * 256 + threadIdx.x;
    if (e >= E_EDGES) return;
    int d = dst[e], t = et[e];
    atomicAdd(&bdeg[(d >> 7) * N_ETYPES + t], 1);
    atomicAdd(&cntT[d * N_ETYPES + t], 1);
}

__global__ __launch_bounds__(1024) void k_scan2(const int* __restrict__ bdeg,
                                                int* __restrict__ bptr, int* __restrict__ bcur) {
    __shared__ int part[1024];
    int tid = threadIdx.x;
    int base = tid * 2;
    int l0 = (base < NBUCK) ? bdeg[base] : 0;
    int l1 = (base + 1 < NBUCK) ? bdeg[base + 1] : 0;
    part[tid] = l0 + l1; __syncthreads();
    for (int off = 1; off < 1024; off <<= 1) {
        int v = (tid >= off) ? part[tid - off] : 0;
        __syncthreads();
        part[tid] += v;
        __syncthreads();
    }
    int excl = (tid > 0) ? part[tid - 1] : 0;
    if (base < NBUCK)     { bptr[base] = excl;          bcur[base] = excl; }
    if (base + 1 < NBUCK) { bptr[base + 1] = excl + l0; bcur[base + 1] = excl + l0; }
    if (tid == 1023) bptr[NBUCK] = part[1023];
}

__global__ __launch_bounds__(256) void k_fill2(const int* __restrict__ src, const int* __restrict__ dst,
                                               const int* __restrict__ et, int* __restrict__ bcur,
                                               int* __restrict__ epk) {
    int e = blockIdx.x * 256 + threadIdx.x;
    if (e >= E_EDGES) return;
    int d = dst[e], t = et[e];
    int b = (d >> 7) * N_ETYPES + t;
    int pos = atomicAdd(&bcur[b], 1);
    epk[pos] = ((d & 127) << 16) | src[e];
}

// prebias[d][c] = sum_t cntT[d][t] * b_e[t][c]
__global__ __launch_bounds__(256) void k_prebias(const int* __restrict__ cntT,
                                                 const float* __restrict__ b_e,
                                                 float* __restrict__ prebias) {
    int idx = blockIdx.x * 256 + threadIdx.x;
    if (idx >= NPAD * HID) return;
    int d = idx >> 7, c = idx & 127;
    float s = 0.f;
    #pragma unroll
    for (int t = 0; t < N_ETYPES; ++t)
        s += (float)cntT[d * N_ETYPES + t] * b_e[t * 128 + c];
    prebias[idx] = s;
}

// ---------------- fused gather + etype-GEMM: a = sum_t g_t @ W_t + prebias ----------------
// grid 236 = 118 row-blocks x 2 col-halves. 512 thr = 8 waves, wave owns 16 dst rows x 64 cols.
__global__ __launch_bounds__(512) void k_abuild(
    const int* __restrict__ bptr, const int* __restrict__ epk,
    const unsigned short* __restrict__ h_hi,
    const uint4* __restrict__ WeH, const uint4* __restrict__ WeL,
    const float* __restrict__ prebias,
    unsigned short* __restrict__ a_hi, unsigned short* __restrict__ a_lo)
{
    __shared__ float g32[128 * 128];          // 64 KB; reused as bf16 hi/lo planes
    char* gb = (char*)g32;
    int rb = blockIdx.x >> 1, ch = blockIdx.x & 1;
    int tid = threadIdx.x;
    int lane = tid & 63, w = tid >> 6;
    int l15 = lane & 15, lsub = lane >> 4;
    int eslot = tid >> 4, j = tid & 15;       // gather: 32 edge slots x 16 threads (16B each)
    int cr = tid >> 2, cc0 = (tid & 3) * 32;  // convert: thread owns row cr, cols cc0..cc0+32

    v4f acc[4];
    #pragma unroll
    for (int c8 = 0; c8 < 4; ++c8) acc[c8] = (v4f)(0.f);

    for (int t = 0; t < N_ETYPES; ++t) {
        // zero g32
        #pragma unroll
        for (int k = 0; k < 8; ++k) ((float4*)g32)[k * 512 + tid] = make_float4(0.f, 0.f, 0.f, 0.f);
        __syncthreads();
        // gather-sum h_hi rows into g32 (LDS f32 atomics)
        {
            int b = rb * N_ETYPES + t;
            int s = bptr[b], e = bptr[b + 1];
            for (int i = s + eslot; i < e; i += 32) {
                int pe = epk[i];
                int dr = pe >> 16, sn = pe & 0xffff;
                uint4 v = ((const uint4*)h_hi)[sn * 16 + j];
                unsigned int uu[4] = {v.x, v.y, v.z, v.w};
                float* grow = &g32[dr * 128 + j * 8];
                #pragma unroll
                for (int q = 0; q < 4; ++q) {
                    atomicAdd(grow + q * 2,     bf2f((unsigned short)(uu[q] & 0xffff)));
                    atomicAdd(grow + q * 2 + 1, bf2f((unsigned short)(uu[q] >> 16)));
                }
            }
        }
        __syncthreads();
        // convert in place: f32 tile -> swizzled bf16 hi plane [0,32KB) + lo plane [32KB,64KB)
        float tmp[32];
        #pragma unroll
        for (int k = 0; k < 32; ++k) tmp[k] = g32[cr * 128 + cc0 + k];
        __syncthreads();
        #pragma unroll
        for (int gch = 0; gch < 4; ++gch) {
            unsigned short hb[8], lb[8];
            #pragma unroll
            for (int k = 0; k < 8; ++k) {
                float v = tmp[gch * 8 + k];
                unsigned short hh = f2bf(v);
                hb[k] = hh; lb[k] = f2bf(v - bf2f(hh));
            }
            int byt = (cr * 256 + (cc0 + gch * 8) * 2) ^ ((cr & 7) << 4);
            *(uint4*)(gb + byt) = *(uint4*)hb;
            *(uint4*)(gb + 32768 + byt) = *(uint4*)lb;
        }
        __syncthreads();
        // load A fragments (swizzled ds_read_b128, 2-way conflict = free)
        FragU ah[4], al[4];
        int row = w * 16 + l15;
        #pragma unroll
        for (int kc = 0; kc < 4; ++kc) {
            int byt = (row * 256 + kc * 64 + lsub * 16) ^ ((row & 7) << 4);
            ah[kc].u = *(const uint4*)(gb + byt);
            al[kc].u = *(const uint4*)(gb + 32768 + byt);
        }
        __syncthreads();   // frags in regs; next-t zero may proceed after this
        // MFMA vs W_t fragments (L2-hot)
        #pragma unroll
        for (int kc = 0; kc < 4; ++kc)
            #pragma unroll
            for (int c8 = 0; c8 < 4; ++c8) {
                int bi = (kc * 4 + lsub) * 128 + ch * 64 + c8 * 16 + l15;
                FragU bh, bl2;
                bh.u = WeH[t * 2048 + bi];
                bl2.u = WeL[t * 2048 + bi];
                acc[c8] = __builtin_amdgcn_mfma_f32_16x16x32_bf16(ah[kc].b, bh.b, acc[c8], 0, 0, 0);
                acc[c8] = __builtin_amdgcn_mfma_f32_16x16x32_bf16(al[kc].b, bh.b, acc[c8], 0, 0, 0);
                acc[c8] = __builtin_amdgcn_mfma_f32_16x16x32_bf16(ah[kc].b, bl2.b, acc[c8], 0, 0, 0);
            }
    }

    // epilogue: + prebias, split hi/lo, store
    int rowg = rb * 128 + w * 16 + lsub * 4;
    #pragma unroll
    for (int c8 = 0; c8 < 4; ++c8) {
        int col = ch * 64 + c8 * 16 + l15;
        #pragma unroll
        for (int i = 0; i < 4; ++i) {
            long off = (long)(rowg + i) * 128 + col;
            float v = acc[c8][i] + prebias[off];
            unsigned short hh = f2bf(v);
            a_hi[off] = hh;
            a_lo[off] = f2bf(v - bf2f(hh));
        }
    }
}

// ---------------- GRU GEMMs: z=0: GI = a@WihT, z=1: GH = h@WhhT (bf16 out) ----------------
__global__ __launch_bounds__(512) void k_ggemm(
    const unsigned short* __restrict__ A0h, const unsigned short* __restrict__ A0l,
    const unsigned short* __restrict__ A1h, const unsigned short* __restrict__ A1l,
    const uint4* __restrict__ B0H, const uint4* __restrict__ B0L,
    const uint4* __restrict__ B1H, const uint4* __restrict__ B1L,
    const float* __restrict__ bias0, const float* __restrict__ bias1,
    unsigned short* __restrict__ C0, unsigned short* __restrict__ C1)
{
    __shared__ uint4 blds[2][2048];          // 64 KB
    int z = blockIdx.z;
    const unsigned short* Ahi = z ? A1h : A0h;
    const unsigned short* Alo = z ? A1l : A0l;
    const uint4* BH = z ? B1H : B0H;
    const uint4* BL = z ? B1L : B0L;
    const float* bias = z ? bias1 : bias0;
    unsigned short* C = z ? C1 : C0;
    int j0 = blockIdx.y * 128;

    int tid = threadIdx.x;
    {
        #pragma unroll
        for (int it = 0; it < 4; ++it) {
            int f = it * 512 + tid;
            int kcsub = f >> 7, c = f & 127;
            int gi = kcsub * 384 + j0 + c;
            blds[0][f] = BH[gi];
            blds[1][f] = BL[gi];
        }
    }
    __syncthreads();

    int lane = tid & 63, w = tid >> 6;
    int r0 = blockIdx.x * 128 + w * 16;
    int l15 = lane & 15, lsub = lane >> 4;

    FragU ah[4], al[4];
    const char* Ahb = (const char*)Ahi;
    const char* Alb = (const char*)Alo;
    #pragma unroll
    for (int kc = 0; kc < 4; ++kc) {
        long boff = (long)(r0 + l15) * 256 + kc * 64 + lsub * 16;
        ah[kc].u = *(const uint4*)(Ahb + boff);
        al[kc].u = *(const uint4*)(Alb + boff);
    }

    v4f acc[8];
    #pragma unroll
    for (int c8 = 0; c8 < 8; ++c8) acc[c8] = (v4f)(0.f);

    #pragma unroll
    for (int kc = 0; kc < 4; ++kc)
        #pragma unroll
        for (int c8 = 0; c8 < 8; ++c8) {
            int bi = (kc * 4 + lsub) * 128 + c8 * 16 + l15;
            FragU bhf, blf; bhf.u = blds[0][bi]; blf.u = blds[1][bi];
            acc[c8] = __builtin_amdgcn_mfma_f32_16x16x32_bf16(ah[kc].b, bhf.b, acc[c8], 0, 0, 0);
            acc[c8] = __builtin_amdgcn_mfma_f32_16x16x32_bf16(al[kc].b, bhf.b, acc[c8], 0, 0, 0);
            acc[c8] = __builtin_amdgcn_mfma_f32_16x16x32_bf16(ah[kc].b, blf.b, acc[c8], 0, 0, 0);
        }

    int rbase = r0 + lsub * 4;
    #pragma unroll
    for (int c8 = 0; c8 < 8; ++c8) {
        int col = j0 + c8 * 16 + l15;
        float bv = bias[col];
        #pragma unroll
        for (int i = 0; i < 4; ++i) {
            int row = rbase + i;
            if (row < N_NODES) C[(long)row * 384 + col] = f2bf(acc[c8][i] + bv);
        }
    }
}

// ---------------- GRU gates (fp32 carry; bf16 hi/lo planes out) ----------------
__global__ __launch_bounds__(256) void k_gates(
    const unsigned short* __restrict__ GI, const unsigned short* __restrict__ GH,
    float* __restrict__ h32,
    unsigned int* __restrict__ h_hi, unsigned int* __restrict__ h_lo)
{
    int idx = blockIdx.x * 256 + threadIdx.x;       // one uint = 2 channels
    if (idx >= N_NODES * 64) return;
    int n = idx >> 6, c2 = idx & 63;
    const unsigned int* gi = (const unsigned int*)(GI + (long)n * 384);
    const unsigned int* gh = (const unsigned int*)(GH + (long)n * 384);
    unsigned int uir = gi[c2], uiz = gi[c2 + 64], uin = gi[c2 + 128];
    unsigned int uhr = gh[c2], uhz = gh[c2 + 64], uhn = gh[c2 + 128];
    float2 ho = ((float2*)h32)[idx];
    float hv[2];
    #pragma unroll
    for (int p = 0; p < 2; ++p) {
        int sh = p * 16;
        float ir = bf2f((unsigned short)(uir >> sh)), iz = bf2f((unsigned short)(uiz >> sh)),
              inn = bf2f((unsigned short)(uin >> sh));
        float hr = bf2f((unsigned short)(uhr >> sh)), hz = bf2f((unsigned short)(uhz >> sh)),
              hn = bf2f((unsigned short)(uhn >> sh));
        float rr = sigm(ir + hr);
        float zg = sigm(iz + hz);
        float ng = tanhf(inn + rr * hn);
        float hov = p ? ho.y : ho.x;
        hv[p] = (1.f - zg) * ng + zg * hov;
    }
    ((float2*)h32)[idx] = make_float2(hv[0], hv[1]);
    unsigned short hi0 = f2bf(hv[0]), hi1 = f2bf(hv[1]);
    h_hi[idx] = (unsigned int)hi0 | ((unsigned int)hi1 << 16);
    unsigned short lo0 = f2bf(hv[0] - bf2f(hi0)), lo1 = f2bf(hv[1] - bf2f(hi1));
    h_lo[idx] = (unsigned int)lo0 | ((unsigned int)lo1 << 16);
}

// ---------------- pooling + classifier ----------------
__global__ __launch_bounds__(256) void k_pool(const float* __restrict__ h32,
                                              const int* __restrict__ gid,
                                              float* __restrict__ hg) {
    int idx = blockIdx.x * 256 + threadIdx.x;
    if (idx >= N_NODES * HID) return;
    int n = idx >> 7, c = idx & 127;
    atomicAdd(&hg[gid[n] * HID + c], h32[idx]);
}

__global__ __launch_bounds__(640) void k_cls(const float* __restrict__ hg,
                                             const float* __restrict__ Wc,
                                             const float* __restrict__ bc,
                                             float* __restrict__ out) {
    int tid = threadIdx.x;
    if (tid >= N_GRAPHS * N_CLASSES) return;
    int g = tid / N_CLASSES, c = tid - g * N_CLASSES;
    float s = bc[c];
    for (int k = 0; k < HID; ++k) s = fmaf(hg[g * HID + k], Wc[c * HID + k], s);
    out[tid] = s;
}

// ---------------- launch ----------------
extern "C" void kernel_launch(void* const* d_in, const int* in_sizes, int n_in,
                              void* d_out, int out_size, void* d_ws, size_t ws_size,
                              hipStream_t stream) {
    const float* feat  = (const float*)d_in[0];
    const int*   src   = (const int*)d_in[1];
    const int*   dst   = (const int*)d_in[2];
    const int*   et    = (const int*)d_in[3];
    const int*   gid   = (const int*)d_in[4];
    const float* W_e   = (const float*)d_in[5];
    const float* b_e   = (const float*)d_in[6];
    const float* W_ih  = (const float*)d_in[7];
    const float* W_hh  = (const float*)d_in[8];
    const float* b_ih  = (const float*)d_in[9];
    const float* b_hh  = (const float*)d_in[10];
    const float* W_cls = (const float*)d_in[11];
    const float* b_cls = (const float*)d_in[12];
    float* out = (float*)d_out;

    char* p = (char*)d_ws;
    auto alloc = [&](size_t bytes) { char* r = p; p += (bytes + 255) & ~(size_t)255; return r; };
    float*          h32  = (float*)alloc((size_t)NPAD * 128 * 4);
    unsigned short* h_hi = (unsigned short*)alloc((size_t)NPAD * 128 * 2);
    unsigned short* h_lo = (unsigned short*)alloc((size_t)NPAD * 128 * 2);
    unsigned short* a_hi = (unsigned short*)alloc((size_t)NPAD * 128 * 2);
    unsigned short* a_lo = (unsigned short*)alloc((size_t)NPAD * 128 * 2);
    unsigned short* GI   = (unsigned short*)alloc((size_t)NPAD * 384 * 2);
    unsigned short* GH   = (unsigned short*)alloc((size_t)NPAD * 384 * 2);
    unsigned short* WeH  = (unsigned short*)alloc((size_t)N_ETYPES * 16384 * 2);
    unsigned short* WeL  = (unsigned short*)alloc((size_t)N_ETYPES * 16384 * 2);
    unsigned short* WihH = (unsigned short*)alloc((size_t)16 * 384 * 8 * 2);
    unsigned short* WihL = (unsigned short*)alloc((size_t)16 * 384 * 8 * 2);
    unsigned short* WhhH = (unsigned short*)alloc((size_t)16 * 384 * 8 * 2);
    unsigned short* WhhL = (unsigned short*)alloc((size_t)16 * 384 * 8 * 2);
    int* bdeg   = (int*)alloc((size_t)NBUCK * 4);
    int* bptr   = (int*)alloc((size_t)(NBUCK + 1) * 4);
    int* bcur   = (int*)alloc((size_t)NBUCK * 4);
    int* epk    = (int*)alloc((size_t)E_EDGES * 4);
    int* cntT   = (int*)alloc((size_t)NPAD * N_ETYPES * 4);
    float* prebias = (float*)alloc((size_t)NPAD * 128 * 4);
    float* hg   = (float*)alloc((size_t)N_GRAPHS * HID * 4);

    // one-time prep
    k_init_h<<<(NPAD * HID + 255) / 256, 256, 0, stream>>>(feat, h32, h_hi, h_lo);
    k_prepW<<<(N_ETYPES * 2048 + 2 * 16 * 384 + 255) / 256, 256, 0, stream>>>(
        W_e, W_ih, W_hh, WeH, WeL, WihH, WihL, WhhH, WhhL);
    k_zero<<<(NBUCK / 4 + 255) / 256, 256, 0, stream>>>((float*)bdeg, (NBUCK + 3) / 4);
    k_zero<<<((NPAD * N_ETYPES) / 4 + 255) / 256, 256, 0, stream>>>((float*)cntT, (NPAD * N_ETYPES) / 4);
    k_count2<<<(E_EDGES + 255) / 256, 256, 0, stream>>>(dst, et, bdeg, cntT);
    k_scan2<<<1, 1024, 0, stream>>>(bdeg, bptr, bcur);
    k_fill2<<<(E_EDGES + 255) / 256, 256, 0, stream>>>(src, dst, et, bcur, epk);
    k_prebias<<<(NPAD * HID + 255) / 256, 256, 0, stream>>>(cntT, b_e, prebias);

    dim3 gG(118, 3, 2);
    for (int step = 0; step < N_STEPS; ++step) {
        k_abuild<<<236, 512, 0, stream>>>(bptr, epk, h_hi,
                                          (const uint4*)WeH, (const uint4*)WeL,
                                          prebias, a_hi, a_lo);
        k_ggemm<<<gG, 512, 0, stream>>>(
            a_hi, a_lo, h_hi, h_lo,
            (const uint4*)WihH, (const uint4*)WihL, (const uint4*)WhhH, (const uint4*)WhhL,
            b_ih, b_hh, GI, GH);
        k_gates<<<(N_NODES * 64 + 255) / 256, 256, 0, stream>>>(
            GI, GH, h32, (unsigned int*)h_hi, (unsigned int*)h_lo);
    }

    k_zero<<<(N_GRAPHS * HID / 4 + 255) / 256, 256, 0, stream>>>(hg, N_GRAPHS * HID / 4);
    k_pool<<<(N_NODES * HID + 255) / 256, 256, 0, stream>>>(h32, gid, hg);
    k_cls<<<1, 640, 0, stream>>>(hg, W_cls, b_cls, out);
}

// Round 7
// 626.433 us; speedup vs baseline: 4.5971x; 4.5971x over previous
//
#include <hip/hip_runtime.h>
#include <math.h>

#define N_NODES 15000
#define NPAD    15104      // 118*128
#define E_EDGES 240000
#define IN_DIM  100
#define HID     128
#define N_ETYPES 13
#define N_STEPS  6
#define N_GRAPHS 64
#define N_CLASSES 10

typedef short v8bf __attribute__((ext_vector_type(8)));
typedef float v4f  __attribute__((ext_vector_type(4)));

union FragU { uint4 u; v8bf b; };

static __device__ __forceinline__ float bf2f(unsigned short u) {
    union { unsigned int i; float f; } x; x.i = ((unsigned int)u) << 16; return x.f;
}
static __device__ __forceinline__ unsigned short f2bf(float f) {
    union { float f; unsigned int i; } x; x.f = f;
    unsigned int u = x.i;
    u = (u + 0x7fff + ((u >> 16) & 1)) >> 16;   // round-nearest-even
    return (unsigned short)u;
}
static __device__ __forceinline__ float sigm(float x) { return 1.f / (1.f + expf(-x)); }

// ---------------- misc ----------------
__global__ __launch_bounds__(256) void k_zero(float* __restrict__ p, long n4) {
    long i = (long)blockIdx.x * 256 + threadIdx.x;
    if (i < n4) ((float4*)p)[i] = make_float4(0.f, 0.f, 0.f, 0.f);
}

__global__ __launch_bounds__(256) void k_init_h(const float* __restrict__ feat,
                                                float* __restrict__ h32,
                                                unsigned short* __restrict__ h_hi,
                                                unsigned short* __restrict__ h_lo) {
    int idx = blockIdx.x * 256 + threadIdx.x;
    if (idx >= NPAD * HID) return;
    int n = idx >> 7, c = idx & 127;
    float v = 0.f;
    if (n < N_NODES && c < IN_DIM) v = feat[n * IN_DIM + c];
    h32[idx] = v;
    unsigned short hi = f2bf(v);
    h_hi[idx] = hi;
    h_lo[idx] = f2bf(v - bf2f(hi));
}

// Weights -> bf16 hi/lo MFMA-fragment planes.
// Frag layout for B[128 x NC]: frag id = kcsub*NC + col (kcsub 0..15), 8 bf16 k=kcsub*8+j.
__global__ __launch_bounds__(256) void k_prepW(
    const float* __restrict__ W_e, const float* __restrict__ W_ih, const float* __restrict__ W_hh,
    unsigned short* __restrict__ WeH, unsigned short* __restrict__ WeL,
    unsigned short* __restrict__ WihH, unsigned short* __restrict__ WihL,
    unsigned short* __restrict__ WhhH, unsigned short* __restrict__ WhhL)
{
    int f = blockIdx.x * 256 + threadIdx.x;
    const int NE = N_ETYPES * 2048;
    const int NG = 16 * 384;
    unsigned short th[8], tl[8];
    if (f < NE) {
        int t = f >> 11, r = f & 2047, kcsub = r >> 7, c = r & 127;
        #pragma unroll
        for (int j = 0; j < 8; ++j) {
            float w = W_e[(long)t * 16384 + (kcsub * 8 + j) * 128 + c];
            th[j] = f2bf(w); tl[j] = f2bf(w - bf2f(th[j]));
        }
        long off = (long)t * 16384 + ((kcsub << 7) + c) * 8;
        *(uint4*)(WeH + off) = *(uint4*)th;
        *(uint4*)(WeL + off) = *(uint4*)tl;
    } else if (f < NE + 2 * NG) {
        int f2 = f - NE;
        const float* srcp = (f2 < NG) ? W_ih : W_hh;
        unsigned short* dh = (f2 < NG) ? WihH : WhhH;
        unsigned short* dl = (f2 < NG) ? WihL : WhhL;
        int g = (f2 < NG) ? f2 : f2 - NG;
        int kcsub = g / 384, c = g - kcsub * 384;
        #pragma unroll
        for (int j = 0; j < 8; ++j) {
            float w = srcp[(long)c * 128 + kcsub * 8 + j];   // B[k][c] = W[c][k]
            th[j] = f2bf(w); tl[j] = f2bf(w - bf2f(th[j]));
        }
        long off = ((long)kcsub * 384 + c) * 8;
        *(uint4*)(dh + off) = *(uint4*)th;
        *(uint4*)(dl + off) = *(uint4*)tl;
    }
}

// ---------------- CSR build ----------------
__global__ __launch_bounds__(256) void k_count(const int* __restrict__ dst, int* __restrict__ deg) {
    int e = blockIdx.x * 256 + threadIdx.x;
    if (e < E_EDGES) atomicAdd(&deg[dst[e]], 1);
}

__global__ __launch_bounds__(1024) void k_scan(const int* __restrict__ deg,
                                               int* __restrict__ rowptr, int* __restrict__ cursor) {
    __shared__ int part[1024];
    int tid = threadIdx.x;
    const int CH = 15;
    int base = tid * CH;
    int local[CH]; int s = 0;
    #pragma unroll
    for (int i = 0; i < CH; ++i) {
        int d = (base + i < NPAD) ? deg[base + i] : 0;
        local[i] = s; s += d;
    }
    part[tid] = s; __syncthreads();
    for (int off = 1; off < 1024; off <<= 1) {
        int v = (tid >= off) ? part[tid - off] : 0;
        __syncthreads();
        part[tid] += v;
        __syncthreads();
    }
    int excl = (tid > 0) ? part[tid - 1] : 0;
    #pragma unroll
    for (int i = 0; i < CH; ++i)
        if (base + i < NPAD) { rowptr[base + i] = excl + local[i]; cursor[base + i] = excl + local[i]; }
    if (tid == 0) rowptr[NPAD] = part[1023];
}

__global__ __launch_bounds__(256) void k_fill(const int* __restrict__ src, const int* __restrict__ dst,
                                              const int* __restrict__ et, int* __restrict__ cursor,
                                              int* __restrict__ eidx) {
    int e = blockIdx.x * 256 + threadIdx.x;
    if (e >= E_EDGES) return;
    int d = dst[e];
    int pos = atomicAdd(&cursor[d], 1);
    eidx[pos] = et[e] * NPAD + src[e];
}

// ---------------- etype GEMM: Wh[t] = h @ W_e[t] + b_e[t] ----------------
// 512 thr = 8 waves; block = 128 rows x 128 cols, one etype; B hi/lo staged in LDS (64 KB).
__global__ __launch_bounds__(512) void k_egemm(
    const unsigned short* __restrict__ Ahi, const unsigned short* __restrict__ Alo,
    const uint4* __restrict__ BH, const uint4* __restrict__ BL,
    const float* __restrict__ bias, unsigned short* __restrict__ C)
{
    __shared__ uint4 blds[2][2048];          // 64 KB
    const int NW = 118 * N_ETYPES;           // 1534
    const int q = NW / 8, r8 = NW % 8;
    int bid = blockIdx.x;
    int xcd = bid & 7, ii = bid >> 3;
    int lid = (xcd < r8 ? xcd * (q + 1) : r8 * (q + 1) + (xcd - r8) * q) + ii;
    int rg = lid / N_ETYPES, t = lid - rg * N_ETYPES;

    int tid = threadIdx.x;
    {
        const uint4* bh = BH + t * 2048;
        const uint4* bl = BL + t * 2048;
        #pragma unroll
        for (int it = 0; it < 4; ++it) {
            int f = it * 512 + tid;
            blds[0][f] = bh[f];
            blds[1][f] = bl[f];
        }
    }
    __syncthreads();

    int lane = tid & 63, w = tid >> 6;
    int r0 = rg * 128 + w * 16;
    int l15 = lane & 15, lsub = lane >> 4;

    FragU ah[4], al[4];
    const char* Ahb = (const char*)Ahi;
    const char* Alb = (const char*)Alo;
    #pragma unroll
    for (int kc = 0; kc < 4; ++kc) {
        long boff = (long)(r0 + l15) * 256 + kc * 64 + lsub * 16;
        ah[kc].u = *(const uint4*)(Ahb + boff);
        al[kc].u = *(const uint4*)(Alb + boff);
    }

    v4f acc[8];
    #pragma unroll
    for (int c8 = 0; c8 < 8; ++c8) acc[c8] = (v4f)(0.f);

    #pragma unroll
    for (int kc = 0; kc < 4; ++kc)
        #pragma unroll
        for (int c8 = 0; c8 < 8; ++c8) {
            int bi = (kc * 4 + lsub) * 128 + c8 * 16 + l15;
            FragU bhf, blf; bhf.u = blds[0][bi]; blf.u = blds[1][bi];
            acc[c8] = __builtin_amdgcn_mfma_f32_16x16x32_bf16(ah[kc].b, bhf.b, acc[c8], 0, 0, 0);
            acc[c8] = __builtin_amdgcn_mfma_f32_16x16x32_bf16(al[kc].b, bhf.b, acc[c8], 0, 0, 0);
            acc[c8] = __builtin_amdgcn_mfma_f32_16x16x32_bf16(ah[kc].b, blf.b, acc[c8], 0, 0, 0);
        }

    const float* bs = bias + t * 128;
    unsigned short* Ct = C + (long)t * NPAD * 128;
    int rbase = r0 + lsub * 4;               // C/D: col = lane&15, row = lsub*4 + i
    #pragma unroll
    for (int c8 = 0; c8 < 8; ++c8) {
        int col = c8 * 16 + l15;
        float bv = bs[col];
        #pragma unroll
        for (int i = 0; i < 4; ++i) {
            int row = rbase + i;
            if (row < N_NODES) Ct[(long)row * 128 + col] = f2bf(acc[c8][i] + bv);
        }
    }
}

// ---------------- CSR aggregation: a[d] = sum Wh[eidx] (bf16 in, fp32 acc, hi/lo out) ----------------
__global__ __launch_bounds__(256) void k_agg(
    const int* __restrict__ rowptr, const int* __restrict__ eidx,
    const unsigned int* __restrict__ Wh,                 // bf16 pairs
    unsigned int* __restrict__ a_hi, unsigned int* __restrict__ a_lo)
{
    int d = blockIdx.x * 4 + (threadIdx.x >> 6);
    if (d >= NPAD) return;
    int lane = threadIdx.x & 63;
    int s = rowptr[d], e = rowptr[d + 1];
    float a0 = 0.f, a1 = 0.f, b0 = 0.f, b1 = 0.f;
    int i = s;
    for (; i + 3 < e; i += 4) {
        int w0 = eidx[i], w1 = eidx[i + 1], w2 = eidx[i + 2], w3 = eidx[i + 3];
        unsigned int v0 = Wh[(long)w0 * 64 + lane];
        unsigned int v1 = Wh[(long)w1 * 64 + lane];
        unsigned int v2 = Wh[(long)w2 * 64 + lane];
        unsigned int v3 = Wh[(long)w3 * 64 + lane];
        a0 += bf2f((unsigned short)(v0 & 0xffff)) + bf2f((unsigned short)(v2 & 0xffff));
        a1 += bf2f((unsigned short)(v0 >> 16))    + bf2f((unsigned short)(v2 >> 16));
        b0 += bf2f((unsigned short)(v1 & 0xffff)) + bf2f((unsigned short)(v3 & 0xffff));
        b1 += bf2f((unsigned short)(v1 >> 16))    + bf2f((unsigned short)(v3 >> 16));
    }
    for (; i < e; ++i) {
        unsigned int v0 = Wh[(long)eidx[i] * 64 + lane];
        a0 += bf2f((unsigned short)(v0 & 0xffff));
        a1 += bf2f((unsigned short)(v0 >> 16));
    }
    a0 += b0; a1 += b1;
    unsigned short h0 = f2bf(a0), h1 = f2bf(a1);
    unsigned short l0 = f2bf(a0 - bf2f(h0)), l1 = f2bf(a1 - bf2f(h1));
    a_hi[(long)d * 64 + lane] = (unsigned int)h0 | ((unsigned int)h1 << 16);
    a_lo[(long)d * 64 + lane] = (unsigned int)l0 | ((unsigned int)l1 << 16);
}

// ---------------- fused GRU: both GEMMs + gates, h updated in place ----------------
// grid 236 x 512 thr. Wave gw = blockIdx*8+w: row-group rgp = gw>>1 (16 rows), col half = gw&1.
// B (Wih/Whh frags, 393 KB total) read straight from L2. No LDS.
__global__ __launch_bounds__(512) void k_gru(
    const unsigned short* __restrict__ a_hi, const unsigned short* __restrict__ a_lo,
    const uint4* __restrict__ WihH, const uint4* __restrict__ WihL,
    const uint4* __restrict__ WhhH, const uint4* __restrict__ WhhL,
    const float* __restrict__ b_ih, const float* __restrict__ b_hh,
    float* __restrict__ h32,
    unsigned short* __restrict__ h_hi, unsigned short* __restrict__ h_lo)
{
    int tid = threadIdx.x, lane = tid & 63, w = tid >> 6;
    int gw = blockIdx.x * 8 + w;
    int rgp = gw >> 1, half = gw & 1;
    int r0 = rgp * 16;
    int l15 = lane & 15, lsub = lane >> 4;

    // A fragments: a (hi/lo) and h (hi/lo) for 16 rows, full K=128
    FragU aa[2][4], hh[2][4];
    {
        const char* ahb = (const char*)a_hi;
        const char* alb = (const char*)a_lo;
        const char* hhb = (const char*)h_hi;
        const char* hlb = (const char*)h_lo;
        #pragma unroll
        for (int kc = 0; kc < 4; ++kc) {
            long boff = (long)(r0 + l15) * 256 + kc * 64 + lsub * 16;
            aa[0][kc].u = *(const uint4*)(ahb + boff);
            aa[1][kc].u = *(const uint4*)(alb + boff);
            hh[0][kc].u = *(const uint4*)(hhb + boff);
            hh[1][kc].u = *(const uint4*)(hlb + boff);
        }
    }
    // paired wave (other col-half) reads all 128 cols of the same h rows:
    // all loads must land before any wave writes h planes.
    __syncthreads();

    #pragma unroll
    for (int u = 0; u < 4; ++u) {
        int cg = half * 4 + u;
        v4f accI[3], accH[3];
        #pragma unroll
        for (int g = 0; g < 3; ++g) { accI[g] = (v4f)(0.f); accH[g] = (v4f)(0.f); }

        #pragma unroll
        for (int kc = 0; kc < 4; ++kc)
            #pragma unroll
            for (int g = 0; g < 3; ++g) {
                int bi = (kc * 4 + lsub) * 384 + g * 128 + cg * 16 + l15;
                FragU wih_h, wih_l, whh_h, whh_l;
                wih_h.u = WihH[bi]; wih_l.u = WihL[bi];
                whh_h.u = WhhH[bi]; whh_l.u = WhhL[bi];
                accI[g] = __builtin_amdgcn_mfma_f32_16x16x32_bf16(aa[0][kc].b, wih_h.b, accI[g], 0, 0, 0);
                accI[g] = __builtin_amdgcn_mfma_f32_16x16x32_bf16(aa[1][kc].b, wih_h.b, accI[g], 0, 0, 0);
                accI[g] = __builtin_amdgcn_mfma_f32_16x16x32_bf16(aa[0][kc].b, wih_l.b, accI[g], 0, 0, 0);
                accH[g] = __builtin_amdgcn_mfma_f32_16x16x32_bf16(hh[0][kc].b, whh_h.b, accH[g], 0, 0, 0);
                accH[g] = __builtin_amdgcn_mfma_f32_16x16x32_bf16(hh[1][kc].b, whh_h.b, accH[g], 0, 0, 0);
                accH[g] = __builtin_amdgcn_mfma_f32_16x16x32_bf16(hh[0][kc].b, whh_l.b, accH[g], 0, 0, 0);
            }

        int c = cg * 16 + l15;
        float bir = b_ih[c], biz = b_ih[c + 128], bin = b_ih[c + 256];
        float bhr = b_hh[c], bhz = b_hh[c + 128], bhn = b_hh[c + 256];
        #pragma unroll
        for (int i = 0; i < 4; ++i) {
            int row = r0 + lsub * 4 + i;
            float ir = accI[0][i] + bir, iz = accI[1][i] + biz, inn = accI[2][i] + bin;
            float hr = accH[0][i] + bhr, hz = accH[1][i] + bhz, hn = accH[2][i] + bhn;
            float rr = sigm(ir + hr);
            float zg = sigm(iz + hz);
            float ng = tanhf(inn + rr * hn);
            long off = (long)row * 128 + c;
            float ho = h32[off];
            float hv = (1.f - zg) * ng + zg * ho;
            h32[off] = hv;
            unsigned short hi_ = f2bf(hv);
            h_hi[off] = hi_;
            h_lo[off] = f2bf(hv - bf2f(hi_));
        }
    }
}

// ---------------- pooling + classifier ----------------
__global__ __launch_bounds__(256) void k_pool(const float* __restrict__ h32,
                                              const int* __restrict__ gid,
                                              float* __restrict__ hg) {
    int idx = blockIdx.x * 256 + threadIdx.x;
    if (idx >= N_NODES * HID) return;
    int n = idx >> 7, c = idx & 127;
    atomicAdd(&hg[gid[n] * HID + c], h32[idx]);
}

__global__ __launch_bounds__(640) void k_cls(const float* __restrict__ hg,
                                             const float* __restrict__ Wc,
                                             const float* __restrict__ bc,
                                             float* __restrict__ out) {
    int tid = threadIdx.x;
    if (tid >= N_GRAPHS * N_CLASSES) return;
    int g = tid / N_CLASSES, c = tid - g * N_CLASSES;
    float s = bc[c];
    for (int k = 0; k < HID; ++k) s = fmaf(hg[g * HID + k], Wc[c * HID + k], s);
    out[tid] = s;
}

// ---------------- launch ----------------
extern "C" void kernel_launch(void* const* d_in, const int* in_sizes, int n_in,
                              void* d_out, int out_size, void* d_ws, size_t ws_size,
                              hipStream_t stream) {
    const float* feat  = (const float*)d_in[0];
    const int*   src   = (const int*)d_in[1];
    const int*   dst   = (const int*)d_in[2];
    const int*   et    = (const int*)d_in[3];
    const int*   gid   = (const int*)d_in[4];
    const float* W_e   = (const float*)d_in[5];
    const float* b_e   = (const float*)d_in[6];
    const float* W_ih  = (const float*)d_in[7];
    const float* W_hh  = (const float*)d_in[8];
    const float* b_ih  = (const float*)d_in[9];
    const float* b_hh  = (const float*)d_in[10];
    const float* W_cls = (const float*)d_in[11];
    const float* b_cls = (const float*)d_in[12];
    float* out = (float*)d_out;

    char* p = (char*)d_ws;
    auto alloc = [&](size_t bytes) { char* r = p; p += (bytes + 255) & ~(size_t)255; return r; };
    float*          h32  = (float*)alloc((size_t)NPAD * 128 * 4);
    unsigned short* h_hi = (unsigned short*)alloc((size_t)NPAD * 128 * 2);
    unsigned short* h_lo = (unsigned short*)alloc((size_t)NPAD * 128 * 2);
    unsigned short* a_hi = (unsigned short*)alloc((size_t)NPAD * 128 * 2);
    unsigned short* a_lo = (unsigned short*)alloc((size_t)NPAD * 128 * 2);
    unsigned short* Wh   = (unsigned short*)alloc((size_t)N_ETYPES * NPAD * 128 * 2);
    unsigned short* WeH  = (unsigned short*)alloc((size_t)N_ETYPES * 16384 * 2);
    unsigned short* WeL  = (unsigned short*)alloc((size_t)N_ETYPES * 16384 * 2);
    unsigned short* WihH = (unsigned short*)alloc((size_t)16 * 384 * 8 * 2);
    unsigned short* WihL = (unsigned short*)alloc((size_t)16 * 384 * 8 * 2);
    unsigned short* WhhH = (unsigned short*)alloc((size_t)16 * 384 * 8 * 2);
    unsigned short* WhhL = (unsigned short*)alloc((size_t)16 * 384 * 8 * 2);
    int* deg    = (int*)alloc((size_t)NPAD * 4);
    int* rowptr = (int*)alloc((size_t)(NPAD + 1) * 4);
    int* cursor = (int*)alloc((size_t)NPAD * 4);
    int* eidx   = (int*)alloc((size_t)E_EDGES * 4);
    float* hg   = (float*)alloc((size_t)N_GRAPHS * HID * 4);

    k_init_h<<<(NPAD * HID + 255) / 256, 256, 0, stream>>>(feat, h32, h_hi, h_lo);
    k_prepW<<<(N_ETYPES * 2048 + 2 * 16 * 384 + 255) / 256, 256, 0, stream>>>(
        W_e, W_ih, W_hh, WeH, WeL, WihH, WihL, WhhH, WhhL);
    k_zero<<<(NPAD / 4 + 255) / 256, 256, 0, stream>>>((float*)deg, NPAD / 4);
    k_count<<<(E_EDGES + 255) / 256, 256, 0, stream>>>(dst, deg);
    k_scan<<<1, 1024, 0, stream>>>(deg, rowptr, cursor);
    k_fill<<<(E_EDGES + 255) / 256, 256, 0, stream>>>(src, dst, et, cursor, eidx);

    for (int step = 0; step < N_STEPS; ++step) {
        k_egemm<<<118 * N_ETYPES, 512, 0, stream>>>(
            h_hi, h_lo, (const uint4*)WeH, (const uint4*)WeL, b_e, Wh);
        k_agg<<<NPAD / 4, 256, 0, stream>>>(rowptr, eidx, (const unsigned int*)Wh,
                                            (unsigned int*)a_hi, (unsigned int*)a_lo);
        k_gru<<<236, 512, 0, stream>>>(
            a_hi, a_lo,
            (const uint4*)WihH, (const uint4*)WihL, (const uint4*)WhhH, (const uint4*)WhhL,
            b_ih, b_hh, h32, h_hi, h_lo);
    }

    k_zero<<<(N_GRAPHS * HID / 4 + 255) / 256, 256, 0, stream>>>(hg, N_GRAPHS * HID / 4);
    k_pool<<<(N_NODES * HID + 255) / 256, 256, 0, stream>>>(h32, gid, hg);
    k_cls<<<1, 640, 0, stream>>>(hg, W_cls, b_cls, out);
}

// Round 8
// 620.083 us; speedup vs baseline: 4.6442x; 1.0102x over previous
//
#include <hip/hip_runtime.h>
#include <math.h>

#define N_NODES 15000
#define NPAD    15104      // 118*128
#define E_EDGES 240000
#define IN_DIM  100
#define HID     128
#define N_ETYPES 13
#define N_STEPS  6
#define N_GRAPHS 64
#define N_CLASSES 10
#define NTS     (N_ETYPES * NPAD)   // 196352 (t,src) cells
#define NSB     384                 // scan blocks of 512

typedef short v8bf __attribute__((ext_vector_type(8)));
typedef float v4f  __attribute__((ext_vector_type(4)));

union FragU { uint4 u; v8bf b; };

static __device__ __forceinline__ float bf2f(unsigned short u) {
    union { unsigned int i; float f; } x; x.i = ((unsigned int)u) << 16; return x.f;
}
static __device__ __forceinline__ unsigned short f2bf(float f) {
    union { float f; unsigned int i; } x; x.f = f;
    unsigned int u = x.i;
    u = (u + 0x7fff + ((u >> 16) & 1)) >> 16;   // round-nearest-even
    return (unsigned short)u;
}
static __device__ __forceinline__ float sigm(float x) { return 1.f / (1.f + expf(-x)); }

// ---------------- misc ----------------
__global__ __launch_bounds__(256) void k_zero(float* __restrict__ p, long n4) {
    long i = (long)blockIdx.x * 256 + threadIdx.x;
    if (i < n4) ((float4*)p)[i] = make_float4(0.f, 0.f, 0.f, 0.f);
}

__global__ __launch_bounds__(256) void k_init_h(const float* __restrict__ feat,
                                                float* __restrict__ h32,
                                                unsigned short* __restrict__ h_hi,
                                                unsigned short* __restrict__ h_lo) {
    int idx = blockIdx.x * 256 + threadIdx.x;
    if (idx >= NPAD * HID) return;
    int n = idx >> 7, c = idx & 127;
    float v = 0.f;
    if (n < N_NODES && c < IN_DIM) v = feat[n * IN_DIM + c];
    h32[idx] = v;
    unsigned short hi = f2bf(v);
    h_hi[idx] = hi;
    h_lo[idx] = f2bf(v - bf2f(hi));
}

// Weights -> bf16 hi/lo MFMA-fragment planes.
__global__ __launch_bounds__(256) void k_prepW(
    const float* __restrict__ W_e, const float* __restrict__ W_ih, const float* __restrict__ W_hh,
    unsigned short* __restrict__ WeH, unsigned short* __restrict__ WeL,
    unsigned short* __restrict__ WihH, unsigned short* __restrict__ WihL,
    unsigned short* __restrict__ WhhH, unsigned short* __restrict__ WhhL)
{
    int f = blockIdx.x * 256 + threadIdx.x;
    const int NE = N_ETYPES * 2048;
    const int NG = 16 * 384;
    unsigned short th[8], tl[8];
    if (f < NE) {
        int t = f >> 11, r = f & 2047, kcsub = r >> 7, c = r & 127;
        #pragma unroll
        for (int j = 0; j < 8; ++j) {
            float w = W_e[(long)t * 16384 + (kcsub * 8 + j) * 128 + c];
            th[j] = f2bf(w); tl[j] = f2bf(w - bf2f(th[j]));
        }
        long off = (long)t * 16384 + ((kcsub << 7) + c) * 8;
        *(uint4*)(WeH + off) = *(uint4*)th;
        *(uint4*)(WeL + off) = *(uint4*)tl;
    } else if (f < NE + 2 * NG) {
        int f2 = f - NE;
        const float* srcp = (f2 < NG) ? W_ih : W_hh;
        unsigned short* dh = (f2 < NG) ? WihH : WhhH;
        unsigned short* dl = (f2 < NG) ? WihL : WhhL;
        int g = (f2 < NG) ? f2 : f2 - NG;
        int kcsub = g / 384, c = g - kcsub * 384;
        #pragma unroll
        for (int j = 0; j < 8; ++j) {
            float w = srcp[(long)c * 128 + kcsub * 8 + j];   // B[k][c] = W[c][k]
            th[j] = f2bf(w); tl[j] = f2bf(w - bf2f(th[j]));
        }
        long off = ((long)kcsub * 384 + c) * 8;
        *(uint4*)(dh + off) = *(uint4*)th;
        *(uint4*)(dl + off) = *(uint4*)tl;
    }
}

// ---------------- graph prep: dst degree + used (t,src) marking ----------------
__global__ __launch_bounds__(256) void k_count_mark(const int* __restrict__ src,
                                                    const int* __restrict__ dst,
                                                    const int* __restrict__ et,
                                                    int* __restrict__ deg,
                                                    int* __restrict__ used) {
    int e = blockIdx.x * 256 + threadIdx.x;
    if (e >= E_EDGES) return;
    atomicAdd(&deg[dst[e]], 1);
    used[et[e] * NPAD + src[e]] = 1;
}

__global__ __launch_bounds__(1024) void k_scan(const int* __restrict__ deg,
                                               int* __restrict__ rowptr, int* __restrict__ cursor) {
    __shared__ int part[1024];
    int tid = threadIdx.x;
    const int CH = 15;
    int base = tid * CH;
    int local[CH]; int s = 0;
    #pragma unroll
    for (int i = 0; i < CH; ++i) {
        int d = (base + i < NPAD) ? deg[base + i] : 0;
        local[i] = s; s += d;
    }
    part[tid] = s; __syncthreads();
    for (int off = 1; off < 1024; off <<= 1) {
        int v = (tid >= off) ? part[tid - off] : 0;
        __syncthreads();
        part[tid] += v;
        __syncthreads();
    }
    int excl = (tid > 0) ? part[tid - 1] : 0;
    #pragma unroll
    for (int i = 0; i < CH; ++i)
        if (base + i < NPAD) { rowptr[base + i] = excl + local[i]; cursor[base + i] = excl + local[i]; }
    if (tid == 0) rowptr[NPAD] = part[1023];
}

// ---- 3-phase scan over used[] -> slot[], rowlist[], tbase[] ----
__global__ __launch_bounds__(512) void k_su1(const int* __restrict__ used, int* __restrict__ bsum) {
    __shared__ int sh[512];
    int tid = threadIdx.x;
    int i = blockIdx.x * 512 + tid;
    sh[tid] = (i < NTS) ? used[i] : 0;
    __syncthreads();
    for (int off = 256; off > 0; off >>= 1) {
        if (tid < off) sh[tid] += sh[tid + off];
        __syncthreads();
    }
    if (tid == 0) bsum[blockIdx.x] = sh[0];
}

__global__ __launch_bounds__(512) void k_su2(const int* __restrict__ bsum, int* __restrict__ bofs) {
    __shared__ int sh[512];
    int tid = threadIdx.x;
    int v = (tid < NSB) ? bsum[tid] : 0;
    sh[tid] = v; __syncthreads();
    for (int off = 1; off < 512; off <<= 1) {
        int u = (tid >= off) ? sh[tid - off] : 0;
        __syncthreads();
        sh[tid] += u;
        __syncthreads();
    }
    if (tid < NSB) bofs[tid] = sh[tid] - v;   // exclusive
}

__global__ __launch_bounds__(512) void k_su3(const int* __restrict__ used,
                                             const int* __restrict__ bofs,
                                             int* __restrict__ slot,
                                             int* __restrict__ rowlist,
                                             int* __restrict__ tbase) {
    __shared__ int sh[512];
    int tid = threadIdx.x;
    int i = blockIdx.x * 512 + tid;
    int f = (i < NTS) ? used[i] : 0;
    sh[tid] = f; __syncthreads();
    for (int off = 1; off < 512; off <<= 1) {
        int u = (tid >= off) ? sh[tid - off] : 0;
        __syncthreads();
        sh[tid] += u;
        __syncthreads();
    }
    int g = bofs[blockIdx.x] + sh[tid] - f;   // global exclusive prefix
    if (i <= NTS) {
        if (i < NTS) slot[i] = g;
        int t = i / NPAD;
        if (i - t * NPAD == 0 || i == NTS) tbase[t] = g;   // i==NTS -> t==13
        if (f) rowlist[g] = i - t * NPAD;
    }
}

__global__ __launch_bounds__(256) void k_fill(const int* __restrict__ src, const int* __restrict__ dst,
                                              const int* __restrict__ et, const int* __restrict__ slot,
                                              int* __restrict__ cursor, int* __restrict__ eidx) {
    int e = blockIdx.x * 256 + threadIdx.x;
    if (e >= E_EDGES) return;
    int d = dst[e];
    int pos = atomicAdd(&cursor[d], 1);
    eidx[pos] = slot[et[e] * NPAD + src[e]];
}

// ---------------- etype GEMM over compacted rows: Wh[gs] = h[rowlist[gs]] @ W_t + b_t ----------------
__global__ __launch_bounds__(512) void k_egemm(
    const unsigned short* __restrict__ Ahi, const unsigned short* __restrict__ Alo,
    const uint4* __restrict__ BH, const uint4* __restrict__ BL,
    const float* __restrict__ bias, const int* __restrict__ tbase,
    const int* __restrict__ rowlist, unsigned short* __restrict__ C)
{
    __shared__ uint4 blds[2][2048];          // 64 KB
    const int NW = 118 * N_ETYPES;           // 1534
    const int q = NW / 8, r8 = NW % 8;
    int bid = blockIdx.x;
    int xcd = bid & 7, ii = bid >> 3;
    int lid = (xcd < r8 ? xcd * (q + 1) : r8 * (q + 1) + (xcd - r8) * q) + ii;
    int rg = lid / N_ETYPES, t = lid - rg * N_ETYPES;

    int base = tbase[t], end = tbase[t + 1];
    if (rg * 128 >= end - base) return;

    int tid = threadIdx.x;
    {
        const uint4* bh = BH + t * 2048;
        const uint4* bl = BL + t * 2048;
        #pragma unroll
        for (int it = 0; it < 4; ++it) {
            int f = it * 512 + tid;
            blds[0][f] = bh[f];
            blds[1][f] = bl[f];
        }
    }
    __syncthreads();

    int lane = tid & 63, w = tid >> 6;
    int gs0 = base + rg * 128 + w * 16;
    int l15 = lane & 15, lsub = lane >> 4;

    int rowslot = gs0 + l15;
    int srcrow = (rowslot < end) ? rowlist[rowslot] : 0;

    FragU ah[4], al[4];
    const char* Ahb = (const char*)Ahi;
    const char* Alb = (const char*)Alo;
    #pragma unroll
    for (int kc = 0; kc < 4; ++kc) {
        long boff = (long)srcrow * 256 + kc * 64 + lsub * 16;
        ah[kc].u = *(const uint4*)(Ahb + boff);
        al[kc].u = *(const uint4*)(Alb + boff);
    }

    v4f acc[8];
    #pragma unroll
    for (int c8 = 0; c8 < 8; ++c8) acc[c8] = (v4f)(0.f);

    #pragma unroll
    for (int kc = 0; kc < 4; ++kc)
        #pragma unroll
        for (int c8 = 0; c8 < 8; ++c8) {
            int bi = (kc * 4 + lsub) * 128 + c8 * 16 + l15;
            FragU bhf, blf; bhf.u = blds[0][bi]; blf.u = blds[1][bi];
            acc[c8] = __builtin_amdgcn_mfma_f32_16x16x32_bf16(ah[kc].b, bhf.b, acc[c8], 0, 0, 0);
            acc[c8] = __builtin_amdgcn_mfma_f32_16x16x32_bf16(al[kc].b, bhf.b, acc[c8], 0, 0, 0);
            acc[c8] = __builtin_amdgcn_mfma_f32_16x16x32_bf16(ah[kc].b, blf.b, acc[c8], 0, 0, 0);
        }

    const float* bs = bias + t * 128;
    int gbase = gs0 + lsub * 4;              // C/D: col = lane&15, row = lsub*4 + i
    #pragma unroll
    for (int c8 = 0; c8 < 8; ++c8) {
        int col = c8 * 16 + l15;
        float bv = bs[col];
        #pragma unroll
        for (int i = 0; i < 4; ++i) {
            int gs2 = gbase + i;
            if (gs2 < end) C[(long)gs2 * 128 + col] = f2bf(acc[c8][i] + bv);
        }
    }
}

// ---------------- CSR aggregation: a[d] = sum Wh[eidx] (bf16 in, fp32 acc, hi/lo out) ----------------
__global__ __launch_bounds__(256) void k_agg(
    const int* __restrict__ rowptr, const int* __restrict__ eidx,
    const unsigned int* __restrict__ Wh,                 // bf16 pairs, slot-indexed
    unsigned int* __restrict__ a_hi, unsigned int* __restrict__ a_lo)
{
    int d = blockIdx.x * 4 + (threadIdx.x >> 6);
    if (d >= NPAD) return;
    int lane = threadIdx.x & 63;
    int s = rowptr[d], e = rowptr[d + 1];
    float a0 = 0.f, a1 = 0.f, b0 = 0.f, b1 = 0.f;
    int i = s;
    for (; i + 3 < e; i += 4) {
        int w0 = eidx[i], w1 = eidx[i + 1], w2 = eidx[i + 2], w3 = eidx[i + 3];
        unsigned int v0 = Wh[(long)w0 * 64 + lane];
        unsigned int v1 = Wh[(long)w1 * 64 + lane];
        unsigned int v2 = Wh[(long)w2 * 64 + lane];
        unsigned int v3 = Wh[(long)w3 * 64 + lane];
        a0 += bf2f((unsigned short)(v0 & 0xffff)) + bf2f((unsigned short)(v2 & 0xffff));
        a1 += bf2f((unsigned short)(v0 >> 16))    + bf2f((unsigned short)(v2 >> 16));
        b0 += bf2f((unsigned short)(v1 & 0xffff)) + bf2f((unsigned short)(v3 & 0xffff));
        b1 += bf2f((unsigned short)(v1 >> 16))    + bf2f((unsigned short)(v3 >> 16));
    }
    for (; i < e; ++i) {
        unsigned int v0 = Wh[(long)eidx[i] * 64 + lane];
        a0 += bf2f((unsigned short)(v0 & 0xffff));
        a1 += bf2f((unsigned short)(v0 >> 16));
    }
    a0 += b0; a1 += b1;
    unsigned short h0 = f2bf(a0), h1 = f2bf(a1);
    unsigned short l0 = f2bf(a0 - bf2f(h0)), l1 = f2bf(a1 - bf2f(h1));
    a_hi[(long)d * 64 + lane] = (unsigned int)h0 | ((unsigned int)h1 << 16);
    a_lo[(long)d * 64 + lane] = (unsigned int)l0 | ((unsigned int)l1 << 16);
}

// ---------------- fused GRU: wave = 16 rows x 16 cols; block = 16 rows x 128 cols ----------------
// grid = NPAD/16 = 944 blocks, 512 thr. Weights (393 KB frags) read from L2.
__global__ __launch_bounds__(512) void k_gru(
    const unsigned short* __restrict__ a_hi, const unsigned short* __restrict__ a_lo,
    const uint4* __restrict__ WihH, const uint4* __restrict__ WihL,
    const uint4* __restrict__ WhhH, const uint4* __restrict__ WhhL,
    const float* __restrict__ b_ih, const float* __restrict__ b_hh,
    float* __restrict__ h32,
    unsigned short* __restrict__ h_hi, unsigned short* __restrict__ h_lo)
{
    int tid = threadIdx.x, lane = tid & 63, cg = tid >> 6;   // cg = wave = col group
    int r0 = blockIdx.x * 16;
    int l15 = lane & 15, lsub = lane >> 4;

    // A fragments: a (hi/lo) and h (hi/lo) for the block's 16 rows, full K=128
    FragU aa[2][4], hh[2][4];
    {
        const char* ahb = (const char*)a_hi;
        const char* alb = (const char*)a_lo;
        const char* hhb = (const char*)h_hi;
        const char* hlb = (const char*)h_lo;
        #pragma unroll
        for (int kc = 0; kc < 4; ++kc) {
            long boff = (long)(r0 + l15) * 256 + kc * 64 + lsub * 16;
            aa[0][kc].u = *(const uint4*)(ahb + boff);
            aa[1][kc].u = *(const uint4*)(alb + boff);
            hh[0][kc].u = *(const uint4*)(hhb + boff);
            hh[1][kc].u = *(const uint4*)(hlb + boff);
        }
    }
    // other waves read all 128 cols of these h rows -> loads must land before in-place writes
    __syncthreads();

    v4f accI[3], accH[3];
    #pragma unroll
    for (int g = 0; g < 3; ++g) { accI[g] = (v4f)(0.f); accH[g] = (v4f)(0.f); }

    #pragma unroll
    for (int kc = 0; kc < 4; ++kc)
        #pragma unroll
        for (int g = 0; g < 3; ++g) {
            int bi = (kc * 4 + lsub) * 384 + g * 128 + cg * 16 + l15;
            FragU wih_h, wih_l, whh_h, whh_l;
            wih_h.u = WihH[bi]; wih_l.u = WihL[bi];
            whh_h.u = WhhH[bi]; whh_l.u = WhhL[bi];
            accI[g] = __builtin_amdgcn_mfma_f32_16x16x32_bf16(aa[0][kc].b, wih_h.b, accI[g], 0, 0, 0);
            accI[g] = __builtin_amdgcn_mfma_f32_16x16x32_bf16(aa[1][kc].b, wih_h.b, accI[g], 0, 0, 0);
            accI[g] = __builtin_amdgcn_mfma_f32_16x16x32_bf16(aa[0][kc].b, wih_l.b, accI[g], 0, 0, 0);
            accH[g] = __builtin_amdgcn_mfma_f32_16x16x32_bf16(hh[0][kc].b, whh_h.b, accH[g], 0, 0, 0);
            accH[g] = __builtin_amdgcn_mfma_f32_16x16x32_bf16(hh[1][kc].b, whh_h.b, accH[g], 0, 0, 0);
            accH[g] = __builtin_amdgcn_mfma_f32_16x16x32_bf16(hh[0][kc].b, whh_l.b, accH[g], 0, 0, 0);
        }

    int c = cg * 16 + l15;
    float bir = b_ih[c], biz = b_ih[c + 128], bin = b_ih[c + 256];
    float bhr = b_hh[c], bhz = b_hh[c + 128], bhn = b_hh[c + 256];
    #pragma unroll
    for (int i = 0; i < 4; ++i) {
        int row = r0 + lsub * 4 + i;
        float ir = accI[0][i] + bir, iz = accI[1][i] + biz, inn = accI[2][i] + bin;
        float hr = accH[0][i] + bhr, hz = accH[1][i] + bhz, hn = accH[2][i] + bhn;
        float rr = sigm(ir + hr);
        float zg = sigm(iz + hz);
        float ng = tanhf(inn + rr * hn);
        long off = (long)row * 128 + c;
        float ho = h32[off];
        float hv = (1.f - zg) * ng + zg * ho;
        if (row < N_NODES) {
            h32[off] = hv;
            unsigned short hi_ = f2bf(hv);
            h_hi[off] = hi_;
            h_lo[off] = f2bf(hv - bf2f(hi_));
        }
    }
}

// ---------------- pooling + classifier ----------------
__global__ __launch_bounds__(256) void k_pool(const float* __restrict__ h32,
                                              const int* __restrict__ gid,
                                              float* __restrict__ hg) {
    int idx = blockIdx.x * 256 + threadIdx.x;
    if (idx >= N_NODES * HID) return;
    int n = idx >> 7, c = idx & 127;
    atomicAdd(&hg[gid[n] * HID + c], h32[idx]);
}

__global__ __launch_bounds__(640) void k_cls(const float* __restrict__ hg,
                                             const float* __restrict__ Wc,
                                             const float* __restrict__ bc,
                                             float* __restrict__ out) {
    int tid = threadIdx.x;
    if (tid >= N_GRAPHS * N_CLASSES) return;
    int g = tid / N_CLASSES, c = tid - g * N_CLASSES;
    float s = bc[c];
    for (int k = 0; k < HID; ++k) s = fmaf(hg[g * HID + k], Wc[c * HID + k], s);
    out[tid] = s;
}

// ---------------- launch ----------------
extern "C" void kernel_launch(void* const* d_in, const int* in_sizes, int n_in,
                              void* d_out, int out_size, void* d_ws, size_t ws_size,
                              hipStream_t stream) {
    const float* feat  = (const float*)d_in[0];
    const int*   src   = (const int*)d_in[1];
    const int*   dst   = (const int*)d_in[2];
    const int*   et    = (const int*)d_in[3];
    const int*   gid   = (const int*)d_in[4];
    const float* W_e   = (const float*)d_in[5];
    const float* b_e   = (const float*)d_in[6];
    const float* W_ih  = (const float*)d_in[7];
    const float* W_hh  = (const float*)d_in[8];
    const float* b_ih  = (const float*)d_in[9];
    const float* b_hh  = (const float*)d_in[10];
    const float* W_cls = (const float*)d_in[11];
    const float* b_cls = (const float*)d_in[12];
    float* out = (float*)d_out;

    char* p = (char*)d_ws;
    auto alloc = [&](size_t bytes) { char* r = p; p += (bytes + 255) & ~(size_t)255; return r; };
    float*          h32  = (float*)alloc((size_t)NPAD * 128 * 4);
    unsigned short* h_hi = (unsigned short*)alloc((size_t)NPAD * 128 * 2);
    unsigned short* h_lo = (unsigned short*)alloc((size_t)NPAD * 128 * 2);
    unsigned short* a_hi = (unsigned short*)alloc((size_t)NPAD * 128 * 2);
    unsigned short* a_lo = (unsigned short*)alloc((size_t)NPAD * 128 * 2);
    unsigned short* Wh   = (unsigned short*)alloc((size_t)NTS * 128 * 2);     // slot-indexed (worst case)
    unsigned short* WeH  = (unsigned short*)alloc((size_t)N_ETYPES * 16384 * 2);
    unsigned short* WeL  = (unsigned short*)alloc((size_t)N_ETYPES * 16384 * 2);
    unsigned short* WihH = (unsigned short*)alloc((size_t)16 * 384 * 8 * 2);
    unsigned short* WihL = (unsigned short*)alloc((size_t)16 * 384 * 8 * 2);
    unsigned short* WhhH = (unsigned short*)alloc((size_t)16 * 384 * 8 * 2);
    unsigned short* WhhL = (unsigned short*)alloc((size_t)16 * 384 * 8 * 2);
    int* deg     = (int*)alloc((size_t)NPAD * 4);
    int* rowptr  = (int*)alloc((size_t)(NPAD + 1) * 4);
    int* cursor  = (int*)alloc((size_t)NPAD * 4);
    int* eidx    = (int*)alloc((size_t)E_EDGES * 4);
    int* used    = (int*)alloc((size_t)NTS * 4);
    int* slot    = (int*)alloc((size_t)NTS * 4);
    int* rowlist = (int*)alloc((size_t)NTS * 4);
    int* bsum    = (int*)alloc((size_t)NSB * 4);
    int* bofs    = (int*)alloc((size_t)NSB * 4);
    int* tbase   = (int*)alloc((size_t)(N_ETYPES + 1) * 4);
    float* hg    = (float*)alloc((size_t)N_GRAPHS * HID * 4);

    // one-time prep
    k_init_h<<<(NPAD * HID + 255) / 256, 256, 0, stream>>>(feat, h32, h_hi, h_lo);
    k_prepW<<<(N_ETYPES * 2048 + 2 * 16 * 384 + 255) / 256, 256, 0, stream>>>(
        W_e, W_ih, W_hh, WeH, WeL, WihH, WihL, WhhH, WhhL);
    k_zero<<<(NPAD / 4 + 255) / 256, 256, 0, stream>>>((float*)deg, NPAD / 4);
    k_zero<<<(NTS / 4 + 255) / 256, 256, 0, stream>>>((float*)used, NTS / 4);
    k_count_mark<<<(E_EDGES + 255) / 256, 256, 0, stream>>>(src, dst, et, deg, used);
    k_scan<<<1, 1024, 0, stream>>>(deg, rowptr, cursor);
    k_su1<<<NSB, 512, 0, stream>>>(used, bsum);
    k_su2<<<1, 512, 0, stream>>>(bsum, bofs);
    k_su3<<<NSB, 512, 0, stream>>>(used, bofs, slot, rowlist, tbase);
    k_fill<<<(E_EDGES + 255) / 256, 256, 0, stream>>>(src, dst, et, slot, cursor, eidx);

    for (int step = 0; step < N_STEPS; ++step) {
        k_egemm<<<118 * N_ETYPES, 512, 0, stream>>>(
            h_hi, h_lo, (const uint4*)WeH, (const uint4*)WeL, b_e, tbase, rowlist, Wh);
        k_agg<<<NPAD / 4, 256, 0, stream>>>(rowptr, eidx, (const unsigned int*)Wh,
                                            (unsigned int*)a_hi, (unsigned int*)a_lo);
        k_gru<<<NPAD / 16, 512, 0, stream>>>(
            a_hi, a_lo,
            (const uint4*)WihH, (const uint4*)WihL, (const uint4*)WhhH, (const uint4*)WhhL,
            b_ih, b_hh, h32, h_hi, h_lo);
    }

    k_zero<<<(N_GRAPHS * HID / 4 + 255) / 256, 256, 0, stream>>>(hg, N_GRAPHS * HID / 4);
    k_pool<<<(N_NODES * HID + 255) / 256, 256, 0, stream>>>(h32, gid, hg);
    k_cls<<<1, 640, 0, stream>>>(hg, W_cls, b_cls, out);
}